// Round 4
// baseline (24058.330 us; speedup 1.0000x reference)
//
#include <hip/hip_runtime.h>
#include <math.h>

// ---------------------------------------------------------------------------
// FNO-GRU 2D: B=16, SX=SY=64, W=64 channels, T=20 steps, YH=33, NFREQ=2112.
// Weights stay in natural [i][o][f] layout (f fastest).
// Workspace (~69 MB):
//   h  : [b][c][x][y] float, 4,194,304
//   B0/B1/B2 : spectral float2 buffers, 2,162,688 each, image-major [img][f].
// Dispatches/step: pw2, fifft_r, pw1, fifft_n, yproj.
// ---------------------------------------------------------------------------

#define NIMG   1024         // B*W images
#define NFREQ  2112         // 64*33
#define IMGSZ  4096         // 64*64
#define INV_N  (1.0f/4096.0f)

typedef float nt4 __attribute__((ext_vector_type(4)));  // native vec for NT loads

__device__ __forceinline__ float4 nt_load4(const float* p) {
    nt4 v = __builtin_nontemporal_load((const nt4*)p);
    return make_float4(v.x, v.y, v.z, v.w);
}

constexpr int brev6(int i) {
    int r = 0;
    for (int b = 0; b < 6; ++b) r |= ((i >> b) & 1) << (5 - b);
    return r;
}

// 64-point complex FFT, fully unrolled radix-2 DIT. DSIGN=-1 fwd, +1 inv.
template <int DSIGN>
__device__ __forceinline__ void fft64(float* xr, float* xi,
                                      const float* cs, const float* sn) {
#pragma unroll
    for (int i = 0; i < 64; ++i) {
        const int j = brev6(i);
        if (j > i) {
            float tr = xr[i]; xr[i] = xr[j]; xr[j] = tr;
            float ti = xi[i]; xi[i] = xi[j]; xi[j] = ti;
        }
    }
#pragma unroll
    for (int s = 1; s <= 6; ++s) {
        const int m = 1 << s, h = m >> 1, step = 64 >> s;
#pragma unroll
        for (int j = 0; j < h; ++j) {
            const int tw = j * step;
            float c = 1.0f, sg = 0.0f;
            if (tw != 0) {
                c  = cs[tw];
                sg = (DSIGN < 0) ? -sn[tw] : sn[tw];
            }
#pragma unroll
            for (int k = j; k < 64; k += m) {
                const int p = k, q = k + h;
                const float vr = xr[q], vi = xi[q];
                float tr, ti;
                if (tw == 0) { tr = vr; ti = vi; }
                else         { tr = c * vr - sg * vi; ti = c * vi + sg * vr; }
                const float ur = xr[p], ui = xi[p];
                xr[p] = ur + tr; xi[p] = ui + ti;
                xr[q] = ur - tr; xi[q] = ui - ti;
            }
        }
    }
}

__device__ __forceinline__ void init_twiddles(float* cs, float* sn, int t) {
    float s, c;
    sincosf(6.28318530717958647692f * (float)t * (1.0f / 64.0f), &s, &c);
    cs[t] = c; sn[t] = s;
}

__device__ __forceinline__ float sigmoidf_(float v) {
    return 1.0f / (1.0f + expf(-v));
}

// ---- shared FFT pass helpers (lds: float2[64*33], row-major [x][k]) -------
// inverse fft along x of column t of F, into lds columns
__device__ __forceinline__ void ifft_pass_x(const float2* __restrict__ F,
                                            float2* lds, const float* cs,
                                            const float* sn, int t) {
    __syncthreads();
    if (t < 33) {
        float ar[64], ai[64];
#pragma unroll
        for (int kx = 0; kx < 64; ++kx) {
            float2 v = F[kx * 33 + t];
            ar[kx] = v.x; ai[kx] = v.y;
        }
        fft64<1>(ar, ai, cs, sn);
#pragma unroll
        for (int x = 0; x < 64; ++x) lds[x * 33 + t] = make_float2(ar[x], ai[x]);
    }
    __syncthreads();
}

// row t: Hermitian-extend + inverse fft along y -> spatial row (unscaled)
__device__ __forceinline__ void ifft_pass_y(const float2* lds, float* xr,
                                            float* xi, const float* cs,
                                            const float* sn, int t) {
#pragma unroll
    for (int k = 0; k <= 32; ++k) {
        float2 v = lds[t * 33 + k];
        xr[k] = v.x; xi[k] = v.y;
    }
#pragma unroll
    for (int k = 33; k < 64; ++k) {
        float2 v = lds[t * 33 + (64 - k)];
        xr[k] = v.x; xi[k] = -v.y;
    }
    fft64<1>(xr, xi, cs, sn);
}

// row t: forward fft along y of real row in xr (xi must be 0), keep 33 -> lds
__device__ __forceinline__ void fwd_pass_y(float* xr, float* xi, float2* lds,
                                           const float* cs, const float* sn,
                                           int t) {
    fft64<-1>(xr, xi, cs, sn);
#pragma unroll
    for (int k = 0; k <= 32; ++k) lds[t * 33 + k] = make_float2(xr[k], xi[k]);
}

// forward fft along x of lds column t -> out image
__device__ __forceinline__ void fwd_pass_x(const float2* lds,
                                           float2* __restrict__ out,
                                           const float* cs, const float* sn,
                                           int t) {
    __syncthreads();
    if (t < 33) {
        float ar[64], ai[64];
#pragma unroll
        for (int x = 0; x < 64; ++x) {
            float2 v = lds[x * 33 + t];
            ar[x] = v.x; ai[x] = v.y;
        }
        fft64<-1>(ar, ai, cs, sn);
#pragma unroll
        for (int kx = 0; kx < 64; ++kx) out[kx * 33 + t] = make_float2(ar[kx], ai[kx]);
    }
}

// ---------------- h0 = x*Wi[c]+bi[c], then rfft2 -> Hf ---------------------
__global__ __launch_bounds__(64) void k_h0fft(const float* __restrict__ x,
                                              const float* __restrict__ Wi,
                                              const float* __restrict__ bi,
                                              float* __restrict__ h,
                                              float2* __restrict__ Hf) {
    __shared__ float cs[64], sn[64];
    __shared__ float2 lds[64 * 33];
    const int t = threadIdx.x;
    init_twiddles(cs, sn, t);
    __syncthreads();
    const int ib = blockIdx.x;        // b*64+c
    const int c = ib & 63, b = ib >> 6;
    const float wi = Wi[c], bc = bi[c];

    float xr[64], xi[64];
    const float4* xrow = (const float4*)(x + (size_t)b * IMGSZ + t * 64);
    float4* hrow = (float4*)(h + (size_t)ib * IMGSZ + t * 64);
#pragma unroll
    for (int k = 0; k < 16; ++k) {
        float4 v = xrow[k];
        v.x = v.x * wi + bc; v.y = v.y * wi + bc;
        v.z = v.z * wi + bc; v.w = v.w * wi + bc;
        hrow[k] = v;
        xr[4 * k + 0] = v.x; xr[4 * k + 1] = v.y;
        xr[4 * k + 2] = v.z; xr[4 * k + 3] = v.w;
    }
#pragma unroll
    for (int k = 0; k < 64; ++k) xi[k] = 0.0f;
    fwd_pass_y(xr, xi, lds, cs, sn, t);
    fwd_pass_x(lds, Hf + (size_t)ib * NFREQ, cs, sn, t);
}

// ---------------- irfft2(Rf) -> r; rh = sigmoid(r)*h; rfft2(rh) -> RHf -----
// (RHf may alias Rf: Rf fully consumed in ifft_pass_x before any write.)
__global__ __launch_bounds__(64) void k_fifft_r(const float2* __restrict__ Rf,
                                                const float* __restrict__ h,
                                                float2* __restrict__ RHf) {
    __shared__ float cs[64], sn[64];
    __shared__ float2 lds[64 * 33];
    const int t = threadIdx.x;
    init_twiddles(cs, sn, t);
    const size_t ib = blockIdx.x;
    float xr[64], xi[64];

    ifft_pass_x(Rf + ib * NFREQ, lds, cs, sn, t);
    ifft_pass_y(lds, xr, xi, cs, sn, t);
    const float4* h4 = (const float4*)(h + ib * IMGSZ + t * 64);
#pragma unroll
    for (int k = 0; k < 16; ++k) {
        float4 hv = h4[k];
        xr[4 * k + 0] = sigmoidf_(xr[4 * k + 0] * INV_N) * hv.x;
        xr[4 * k + 1] = sigmoidf_(xr[4 * k + 1] * INV_N) * hv.y;
        xr[4 * k + 2] = sigmoidf_(xr[4 * k + 2] * INV_N) * hv.z;
        xr[4 * k + 3] = sigmoidf_(xr[4 * k + 3] * INV_N) * hv.w;
    }
#pragma unroll
    for (int k = 0; k < 64; ++k) xi[k] = 0.0f;
    fwd_pass_y(xr, xi, lds, cs, sn, t);      // own-row r/w only, no hazard
    fwd_pass_x(lds, RHf + ib * NFREQ, cs, sn, t);
}

// ---- irfft2(Zf)->z, irfft2(Nf)->n, h=(1-z)h+z*tanh(n); write h + rfft2(h) -
// (Hfn may alias Nf.)
__global__ __launch_bounds__(64) void k_fifft_n(const float2* __restrict__ Nf,
                                                const float2* __restrict__ Zf,
                                                float* __restrict__ h,
                                                float2* __restrict__ Hfn) {
    __shared__ float cs[64], sn[64];
    __shared__ float2 lds[64 * 33];
    __shared__ float zbuf[64 * 64];
    const int t = threadIdx.x;
    init_twiddles(cs, sn, t);
    const size_t ib = blockIdx.x;
    float xr[64], xi[64];

    ifft_pass_x(Zf + ib * NFREQ, lds, cs, sn, t);
    ifft_pass_y(lds, xr, xi, cs, sn, t);
#pragma unroll
    for (int k = 0; k < 64; ++k) zbuf[t * 64 + k] = sigmoidf_(xr[k] * INV_N);

    ifft_pass_x(Nf + ib * NFREQ, lds, cs, sn, t);
    ifft_pass_y(lds, xr, xi, cs, sn, t);
    float4* h4 = (float4*)(h + ib * IMGSZ + t * 64);
    const float4* z4 = (const float4*)(zbuf + t * 64);
#pragma unroll
    for (int k = 0; k < 16; ++k) {
        float4 hv = h4[k];
        float4 zv = z4[k];
        hv.x = (1.0f - zv.x) * hv.x + zv.x * tanhf(xr[4 * k + 0] * INV_N);
        hv.y = (1.0f - zv.y) * hv.y + zv.y * tanhf(xr[4 * k + 1] * INV_N);
        hv.z = (1.0f - zv.z) * hv.z + zv.z * tanhf(xr[4 * k + 2] * INV_N);
        hv.w = (1.0f - zv.w) * hv.w + zv.w * tanhf(xr[4 * k + 3] * INV_N);
        h4[k] = hv;
        xr[4 * k + 0] = hv.x; xr[4 * k + 1] = hv.y;
        xr[4 * k + 2] = hv.z; xr[4 * k + 3] = hv.w;
    }
#pragma unroll
    for (int k = 0; k < 64; ++k) xi[k] = 0.0f;
    fwd_pass_y(xr, xi, lds, cs, sn, t);
    fwd_pass_x(lds, Hfn + ib * NFREQ, cs, sn, t);
}

// ---------------- pointwise complex channel mix ----------------------------
// O[b][o][f] = sum_i H[b][i][f] * w[i][o][f]   (complex)
// grid (66, 8, 2): x = 32-complex-freq tile, y = 8-o group, z = 8-b group.
// lane = (o2<<3)|fq: fq float4 spans 4 cf (full 128B weight line per 8 lanes
// x 8 o rows per wave); wave covers 2 b. 2-slot software pipeline on all
// loads; weights nontemporal (preserve L3 for state).
__device__ __forceinline__ void cmadd4(float (&are)[4], float (&aim)[4],
                                       const float4 hA, const float4 hB,
                                       const float4 wr, const float4 wi) {
    are[0] += hA.x * wr.x - hA.y * wi.x;  aim[0] += hA.x * wi.x + hA.y * wr.x;
    are[1] += hA.z * wr.y - hA.w * wi.y;  aim[1] += hA.z * wi.y + hA.w * wr.y;
    are[2] += hB.x * wr.z - hB.y * wi.z;  aim[2] += hB.x * wi.z + hB.y * wr.z;
    are[3] += hB.z * wr.w - hB.w * wi.w;  aim[3] += hB.z * wi.w + hB.w * wr.w;
}

__global__ __launch_bounds__(256) void k_pw2(const float2* __restrict__ Hf,
                                             const float* __restrict__ wzr,
                                             const float* __restrict__ wzi,
                                             const float* __restrict__ wrr,
                                             const float* __restrict__ wri,
                                             float2* __restrict__ Zf,
                                             float2* __restrict__ Rf) {
    const int t = threadIdx.x;
    const int fq = t & 7;
    const int o  = blockIdx.y * 8 + ((t >> 3) & 7);
    const int b0 = blockIdx.z * 8 + (t >> 6) * 2;
    const int fA = blockIdx.x * 32 + fq * 4;

    float zre[2][4], zim[2][4], rre[2][4], rim[2][4];
#pragma unroll
    for (int b = 0; b < 2; ++b)
#pragma unroll
        for (int k = 0; k < 4; ++k) {
            zre[b][k] = 0.0f; zim[b][k] = 0.0f;
            rre[b][k] = 0.0f; rim[b][k] = 0.0f;
        }

    const size_t w0 = (size_t)o * NFREQ + fA;
    const size_t wstep = (size_t)64 * NFREQ;
    const float2* h0p = Hf + (size_t)(b0 * 64) * NFREQ + fA;
    const float2* h1p = h0p + (size_t)64 * NFREQ;

    float4 wzr_s[2], wzi_s[2], wrr_s[2], wri_s[2];
    float4 hA_s[2][2], hB_s[2][2];

    {
        wzr_s[0] = nt_load4(wzr + w0);
        wzi_s[0] = nt_load4(wzi + w0);
        wrr_s[0] = nt_load4(wrr + w0);
        wri_s[0] = nt_load4(wri + w0);
        const float4* ha = (const float4*)h0p;
        const float4* hb = (const float4*)h1p;
        hA_s[0][0] = ha[0]; hB_s[0][0] = ha[1];
        hA_s[0][1] = hb[0]; hB_s[0][1] = hb[1];
    }
#pragma unroll
    for (int i = 0; i < 64; ++i) {
        const int cur = i & 1, nxt = cur ^ 1;
        if (i < 63) {
            const size_t wo = w0 + (size_t)(i + 1) * wstep;
            wzr_s[nxt] = nt_load4(wzr + wo);
            wzi_s[nxt] = nt_load4(wzi + wo);
            wrr_s[nxt] = nt_load4(wrr + wo);
            wri_s[nxt] = nt_load4(wri + wo);
            const float4* ha = (const float4*)(h0p + (size_t)(i + 1) * NFREQ);
            const float4* hb = (const float4*)(h1p + (size_t)(i + 1) * NFREQ);
            hA_s[nxt][0] = ha[0]; hB_s[nxt][0] = ha[1];
            hA_s[nxt][1] = hb[0]; hB_s[nxt][1] = hb[1];
        }
#pragma unroll
        for (int b = 0; b < 2; ++b) {
            cmadd4(zre[b], zim[b], hA_s[cur][b], hB_s[cur][b], wzr_s[cur], wzi_s[cur]);
            cmadd4(rre[b], rim[b], hA_s[cur][b], hB_s[cur][b], wrr_s[cur], wri_s[cur]);
        }
    }
#pragma unroll
    for (int b = 0; b < 2; ++b) {
        float4* pz = (float4*)(Zf + (size_t)((b0 + b) * 64 + o) * NFREQ + fA);
        float4* pr = (float4*)(Rf + (size_t)((b0 + b) * 64 + o) * NFREQ + fA);
        pz[0] = make_float4(zre[b][0], zim[b][0], zre[b][1], zim[b][1]);
        pz[1] = make_float4(zre[b][2], zim[b][2], zre[b][3], zim[b][3]);
        pr[0] = make_float4(rre[b][0], rim[b][0], rre[b][1], rim[b][1]);
        pr[1] = make_float4(rre[b][2], rim[b][2], rre[b][3], rim[b][3]);
    }
}

__global__ __launch_bounds__(256) void k_pw1(const float2* __restrict__ Hf,
                                             const float* __restrict__ whr,
                                             const float* __restrict__ whi,
                                             float2* __restrict__ Of) {
    const int t = threadIdx.x;
    const int fq = t & 7;
    const int o  = blockIdx.y * 8 + ((t >> 3) & 7);
    const int b0 = blockIdx.z * 8 + (t >> 6) * 2;
    const int fA = blockIdx.x * 32 + fq * 4;

    float cre[2][4], cim[2][4];
#pragma unroll
    for (int b = 0; b < 2; ++b)
#pragma unroll
        for (int k = 0; k < 4; ++k) { cre[b][k] = 0.0f; cim[b][k] = 0.0f; }

    const size_t w0 = (size_t)o * NFREQ + fA;
    const size_t wstep = (size_t)64 * NFREQ;
    const float2* h0p = Hf + (size_t)(b0 * 64) * NFREQ + fA;
    const float2* h1p = h0p + (size_t)64 * NFREQ;

    float4 wr_s[2], wi_s[2];
    float4 hA_s[2][2], hB_s[2][2];
    {
        wr_s[0] = nt_load4(whr + w0);
        wi_s[0] = nt_load4(whi + w0);
        const float4* ha = (const float4*)h0p;
        const float4* hb = (const float4*)h1p;
        hA_s[0][0] = ha[0]; hB_s[0][0] = ha[1];
        hA_s[0][1] = hb[0]; hB_s[0][1] = hb[1];
    }
#pragma unroll
    for (int i = 0; i < 64; ++i) {
        const int cur = i & 1, nxt = cur ^ 1;
        if (i < 63) {
            const size_t wo = w0 + (size_t)(i + 1) * wstep;
            wr_s[nxt] = nt_load4(whr + wo);
            wi_s[nxt] = nt_load4(whi + wo);
            const float4* ha = (const float4*)(h0p + (size_t)(i + 1) * NFREQ);
            const float4* hb = (const float4*)(h1p + (size_t)(i + 1) * NFREQ);
            hA_s[nxt][0] = ha[0]; hB_s[nxt][0] = ha[1];
            hA_s[nxt][1] = hb[0]; hB_s[nxt][1] = hb[1];
        }
#pragma unroll
        for (int b = 0; b < 2; ++b)
            cmadd4(cre[b], cim[b], hA_s[cur][b], hB_s[cur][b], wr_s[cur], wi_s[cur]);
    }
#pragma unroll
    for (int b = 0; b < 2; ++b) {
        float4* po = (float4*)(Of + (size_t)((b0 + b) * 64 + o) * NFREQ + fA);
        po[0] = make_float4(cre[b][0], cim[b][0], cre[b][1], cim[b][1]);
        po[1] = make_float4(cre[b][2], cim[b][2], cre[b][3], cim[b][3]);
    }
}

// ---------------- y = h @ Wo + bo, per step --------------------------------
__global__ __launch_bounds__(256) void k_yproj(const float* __restrict__ h,
                                               const float* __restrict__ Wo,
                                               const float* __restrict__ bo,
                                               float* __restrict__ out,
                                               int step) {
    __shared__ float wo[64];
    const int t = threadIdx.x;
    if (t < 64) wo[t] = Wo[t];
    __syncthreads();
    const int b = blockIdx.x >> 4, xg = blockIdx.x & 15;
    const int xx = xg * 4 + (t >> 6), y = t & 63;
    const float* hp = h + (size_t)b * 64 * IMGSZ + xx * 64 + y;
    float acc = bo[0];
#pragma unroll 8
    for (int c = 0; c < 64; ++c) acc += hp[(size_t)c * IMGSZ] * wo[c];
    out[((size_t)b * 20 + step) * IMGSZ + xx * 64 + y] = acc;
}

// ---------------------------------------------------------------------------
extern "C" void kernel_launch(void* const* d_in, const int* in_sizes, int n_in,
                              void* d_out, int out_size, void* d_ws, size_t ws_size,
                              hipStream_t stream) {
    const float* x    = (const float*)d_in[0];
    // d_in[1] = num_time_steps (always 20 per setup_inputs)
    const float* Wi   = (const float*)d_in[2];
    const float* bi   = (const float*)d_in[3];
    const float* Wo   = (const float*)d_in[4];
    const float* bo   = (const float*)d_in[5];
    const float* Wz_r = (const float*)d_in[6];
    const float* Wz_i = (const float*)d_in[7];
    const float* Wr_r = (const float*)d_in[8];
    const float* Wr_i = (const float*)d_in[9];
    const float* Wh_r = (const float*)d_in[10];
    const float* Wh_i = (const float*)d_in[11];

    float* ws = (float*)d_ws;
    float* h = ws;                              // 4,194,304 floats
    float2* B0 = (float2*)(ws + 4194304);       // 2,162,688 float2 each
    float2* B1 = B0 + 2162688;
    float2* B2 = B1 + 2162688;
    float* outp = (float*)d_out;

    k_h0fft<<<NIMG, 64, 0, stream>>>(x, Wi, bi, h, B0);   // h0, Hf -> B0

    for (int t = 0; t < 20; ++t) {
        k_pw2<<<dim3(66, 8, 2), 256, 0, stream>>>(B0, Wz_r, Wz_i, Wr_r, Wr_i,
                                                  B1, B2);  // Zf->B1 Rf->B2
        k_fifft_r<<<NIMG, 64, 0, stream>>>(B2, h, B2);      // RHf -> B2
        k_pw1<<<dim3(66, 8, 2), 256, 0, stream>>>(B2, Wh_r, Wh_i, B0); // Nf->B0
        k_fifft_n<<<NIMG, 64, 0, stream>>>(B0, B1, h, B0);  // h, Hf_next -> B0
        k_yproj<<<256, 256, 0, stream>>>(h, Wo, bo, outp, t);
    }
}

// Round 5
// 6217.135 us; speedup vs baseline: 3.8697x; 3.8697x over previous
//
#include <hip/hip_runtime.h>
#include <math.h>

// ---------------------------------------------------------------------------
// FNO-GRU 2D: B=16, SX=SY=64, W=64 channels, T=20 steps, YH=33, NFREQ=2112.
// Weights stay in natural [i][o][f] layout (f fastest).
// Workspace (~69 MB):
//   h  : [b][c][x][y] float, 4,194,304
//   B0/B1/B2 : spectral float2 buffers, 2,162,688 each, image-major [img][f].
// Dispatches/step: pw2, fifft_r, pw1, fifft_n, yproj.
// NOTE (round-4 post-mortem): manual software-pipeline arrays + full unroll
// drove VGPR to 256 and spilled accumulators to scratch (1.1 GB WRITE_SIZE
// per pw2 dispatch, 24 ms total). Direct loads + unroll 2 compile to ~92
// VGPR and stay spill-free. Weights are NOT nontemporal: all 6 tensors =
// 207 MB < 256 MB L3, so they stay Infinity-Cache-resident across steps.
// ---------------------------------------------------------------------------

#define NIMG   1024         // B*W images
#define NFREQ  2112         // 64*33
#define IMGSZ  4096         // 64*64
#define INV_N  (1.0f/4096.0f)

constexpr int brev6(int i) {
    int r = 0;
    for (int b = 0; b < 6; ++b) r |= ((i >> b) & 1) << (5 - b);
    return r;
}

// 64-point complex FFT, fully unrolled radix-2 DIT. DSIGN=-1 fwd, +1 inv.
template <int DSIGN>
__device__ __forceinline__ void fft64(float* xr, float* xi,
                                      const float* cs, const float* sn) {
#pragma unroll
    for (int i = 0; i < 64; ++i) {
        const int j = brev6(i);
        if (j > i) {
            float tr = xr[i]; xr[i] = xr[j]; xr[j] = tr;
            float ti = xi[i]; xi[i] = xi[j]; xi[j] = ti;
        }
    }
#pragma unroll
    for (int s = 1; s <= 6; ++s) {
        const int m = 1 << s, h = m >> 1, step = 64 >> s;
#pragma unroll
        for (int j = 0; j < h; ++j) {
            const int tw = j * step;
            float c = 1.0f, sg = 0.0f;
            if (tw != 0) {
                c  = cs[tw];
                sg = (DSIGN < 0) ? -sn[tw] : sn[tw];
            }
#pragma unroll
            for (int k = j; k < 64; k += m) {
                const int p = k, q = k + h;
                const float vr = xr[q], vi = xi[q];
                float tr, ti;
                if (tw == 0) { tr = vr; ti = vi; }
                else         { tr = c * vr - sg * vi; ti = c * vi + sg * vr; }
                const float ur = xr[p], ui = xi[p];
                xr[p] = ur + tr; xi[p] = ui + ti;
                xr[q] = ur - tr; xi[q] = ui - ti;
            }
        }
    }
}

__device__ __forceinline__ void init_twiddles(float* cs, float* sn, int t) {
    float s, c;
    sincosf(6.28318530717958647692f * (float)t * (1.0f / 64.0f), &s, &c);
    cs[t] = c; sn[t] = s;
}

__device__ __forceinline__ float sigmoidf_(float v) {
    return 1.0f / (1.0f + expf(-v));
}

// ---- shared FFT pass helpers (lds: float2[64*33], row-major [x][k]) -------
// inverse fft along x of column t of F, into lds columns
__device__ __forceinline__ void ifft_pass_x(const float2* __restrict__ F,
                                            float2* lds, const float* cs,
                                            const float* sn, int t) {
    __syncthreads();
    if (t < 33) {
        float ar[64], ai[64];
#pragma unroll
        for (int kx = 0; kx < 64; ++kx) {
            float2 v = F[kx * 33 + t];
            ar[kx] = v.x; ai[kx] = v.y;
        }
        fft64<1>(ar, ai, cs, sn);
#pragma unroll
        for (int x = 0; x < 64; ++x) lds[x * 33 + t] = make_float2(ar[x], ai[x]);
    }
    __syncthreads();
}

// row t: Hermitian-extend + inverse fft along y -> spatial row (unscaled)
__device__ __forceinline__ void ifft_pass_y(const float2* lds, float* xr,
                                            float* xi, const float* cs,
                                            const float* sn, int t) {
#pragma unroll
    for (int k = 0; k <= 32; ++k) {
        float2 v = lds[t * 33 + k];
        xr[k] = v.x; xi[k] = v.y;
    }
#pragma unroll
    for (int k = 33; k < 64; ++k) {
        float2 v = lds[t * 33 + (64 - k)];
        xr[k] = v.x; xi[k] = -v.y;
    }
    fft64<1>(xr, xi, cs, sn);
}

// row t: forward fft along y of real row in xr (xi must be 0), keep 33 -> lds
__device__ __forceinline__ void fwd_pass_y(float* xr, float* xi, float2* lds,
                                           const float* cs, const float* sn,
                                           int t) {
    fft64<-1>(xr, xi, cs, sn);
#pragma unroll
    for (int k = 0; k <= 32; ++k) lds[t * 33 + k] = make_float2(xr[k], xi[k]);
}

// forward fft along x of lds column t -> out image
__device__ __forceinline__ void fwd_pass_x(const float2* lds,
                                           float2* __restrict__ out,
                                           const float* cs, const float* sn,
                                           int t) {
    __syncthreads();
    if (t < 33) {
        float ar[64], ai[64];
#pragma unroll
        for (int x = 0; x < 64; ++x) {
            float2 v = lds[x * 33 + t];
            ar[x] = v.x; ai[x] = v.y;
        }
        fft64<-1>(ar, ai, cs, sn);
#pragma unroll
        for (int kx = 0; kx < 64; ++kx) out[kx * 33 + t] = make_float2(ar[kx], ai[kx]);
    }
}

// ---------------- h0 = x*Wi[c]+bi[c], then rfft2 -> Hf ---------------------
__global__ __launch_bounds__(64) void k_h0fft(const float* __restrict__ x,
                                              const float* __restrict__ Wi,
                                              const float* __restrict__ bi,
                                              float* __restrict__ h,
                                              float2* __restrict__ Hf) {
    __shared__ float cs[64], sn[64];
    __shared__ float2 lds[64 * 33];
    const int t = threadIdx.x;
    init_twiddles(cs, sn, t);
    __syncthreads();
    const int ib = blockIdx.x;        // b*64+c
    const int c = ib & 63, b = ib >> 6;
    const float wi = Wi[c], bc = bi[c];

    float xr[64], xi[64];
    const float4* xrow = (const float4*)(x + (size_t)b * IMGSZ + t * 64);
    float4* hrow = (float4*)(h + (size_t)ib * IMGSZ + t * 64);
#pragma unroll
    for (int k = 0; k < 16; ++k) {
        float4 v = xrow[k];
        v.x = v.x * wi + bc; v.y = v.y * wi + bc;
        v.z = v.z * wi + bc; v.w = v.w * wi + bc;
        hrow[k] = v;
        xr[4 * k + 0] = v.x; xr[4 * k + 1] = v.y;
        xr[4 * k + 2] = v.z; xr[4 * k + 3] = v.w;
    }
#pragma unroll
    for (int k = 0; k < 64; ++k) xi[k] = 0.0f;
    fwd_pass_y(xr, xi, lds, cs, sn, t);
    fwd_pass_x(lds, Hf + (size_t)ib * NFREQ, cs, sn, t);
}

// ---------------- irfft2(Rf) -> r; rh = sigmoid(r)*h; rfft2(rh) -> RHf -----
// (RHf may alias Rf: Rf fully consumed in ifft_pass_x before any write.)
__global__ __launch_bounds__(64) void k_fifft_r(const float2* __restrict__ Rf,
                                                const float* __restrict__ h,
                                                float2* __restrict__ RHf) {
    __shared__ float cs[64], sn[64];
    __shared__ float2 lds[64 * 33];
    const int t = threadIdx.x;
    init_twiddles(cs, sn, t);
    const size_t ib = blockIdx.x;
    float xr[64], xi[64];

    ifft_pass_x(Rf + ib * NFREQ, lds, cs, sn, t);
    ifft_pass_y(lds, xr, xi, cs, sn, t);
    const float4* h4 = (const float4*)(h + ib * IMGSZ + t * 64);
#pragma unroll
    for (int k = 0; k < 16; ++k) {
        float4 hv = h4[k];
        xr[4 * k + 0] = sigmoidf_(xr[4 * k + 0] * INV_N) * hv.x;
        xr[4 * k + 1] = sigmoidf_(xr[4 * k + 1] * INV_N) * hv.y;
        xr[4 * k + 2] = sigmoidf_(xr[4 * k + 2] * INV_N) * hv.z;
        xr[4 * k + 3] = sigmoidf_(xr[4 * k + 3] * INV_N) * hv.w;
    }
#pragma unroll
    for (int k = 0; k < 64; ++k) xi[k] = 0.0f;
    fwd_pass_y(xr, xi, lds, cs, sn, t);      // own-row r/w only, no hazard
    fwd_pass_x(lds, RHf + ib * NFREQ, cs, sn, t);
}

// ---- irfft2(Zf)->z, irfft2(Nf)->n, h=(1-z)h+z*tanh(n); write h + rfft2(h) -
// (Hfn may alias Nf.)
__global__ __launch_bounds__(64) void k_fifft_n(const float2* __restrict__ Nf,
                                                const float2* __restrict__ Zf,
                                                float* __restrict__ h,
                                                float2* __restrict__ Hfn) {
    __shared__ float cs[64], sn[64];
    __shared__ float2 lds[64 * 33];
    __shared__ float zbuf[64 * 64];
    const int t = threadIdx.x;
    init_twiddles(cs, sn, t);
    const size_t ib = blockIdx.x;
    float xr[64], xi[64];

    ifft_pass_x(Zf + ib * NFREQ, lds, cs, sn, t);
    ifft_pass_y(lds, xr, xi, cs, sn, t);
#pragma unroll
    for (int k = 0; k < 64; ++k) zbuf[t * 64 + k] = sigmoidf_(xr[k] * INV_N);

    ifft_pass_x(Nf + ib * NFREQ, lds, cs, sn, t);
    ifft_pass_y(lds, xr, xi, cs, sn, t);
    float4* h4 = (float4*)(h + ib * IMGSZ + t * 64);
    const float4* z4 = (const float4*)(zbuf + t * 64);
#pragma unroll
    for (int k = 0; k < 16; ++k) {
        float4 hv = h4[k];
        float4 zv = z4[k];
        hv.x = (1.0f - zv.x) * hv.x + zv.x * tanhf(xr[4 * k + 0] * INV_N);
        hv.y = (1.0f - zv.y) * hv.y + zv.y * tanhf(xr[4 * k + 1] * INV_N);
        hv.z = (1.0f - zv.z) * hv.z + zv.z * tanhf(xr[4 * k + 2] * INV_N);
        hv.w = (1.0f - zv.w) * hv.w + zv.w * tanhf(xr[4 * k + 3] * INV_N);
        h4[k] = hv;
        xr[4 * k + 0] = hv.x; xr[4 * k + 1] = hv.y;
        xr[4 * k + 2] = hv.z; xr[4 * k + 3] = hv.w;
    }
#pragma unroll
    for (int k = 0; k < 64; ++k) xi[k] = 0.0f;
    fwd_pass_y(xr, xi, lds, cs, sn, t);
    fwd_pass_x(lds, Hfn + ib * NFREQ, cs, sn, t);
}

// ---------------- pointwise complex channel mix ----------------------------
// O[b][o][f] = sum_i H[b][i][f] * w[i][o][f]   (complex)
// grid (66, 8, 2): x = 32-complex-freq tile, y = 8-o group, z = 8-b group.
// lane = (o2<<3)|fq: fq float4 spans 4 cf; the 8 fq lanes cover one full
// 128 B weight line per (i,o). Direct loads, unroll 2 (spill-free ~92 VGPR).
__device__ __forceinline__ void cmadd4(float (&are)[4], float (&aim)[4],
                                       const float4 hA, const float4 hB,
                                       const float4 wr, const float4 wi) {
    are[0] += hA.x * wr.x - hA.y * wi.x;  aim[0] += hA.x * wi.x + hA.y * wr.x;
    are[1] += hA.z * wr.y - hA.w * wi.y;  aim[1] += hA.z * wi.y + hA.w * wr.y;
    are[2] += hB.x * wr.z - hB.y * wi.z;  aim[2] += hB.x * wi.z + hB.y * wr.z;
    are[3] += hB.z * wr.w - hB.w * wi.w;  aim[3] += hB.z * wi.w + hB.w * wr.w;
}

__global__ __launch_bounds__(256) void k_pw2(const float2* __restrict__ Hf,
                                             const float* __restrict__ wzr,
                                             const float* __restrict__ wzi,
                                             const float* __restrict__ wrr,
                                             const float* __restrict__ wri,
                                             float2* __restrict__ Zf,
                                             float2* __restrict__ Rf) {
    const int t = threadIdx.x;
    const int fq = t & 7;
    const int o  = blockIdx.y * 8 + ((t >> 3) & 7);
    const int b0 = blockIdx.z * 8 + (t >> 6) * 2;
    const int fA = blockIdx.x * 32 + fq * 4;

    float zre[2][4], zim[2][4], rre[2][4], rim[2][4];
#pragma unroll
    for (int b = 0; b < 2; ++b)
#pragma unroll
        for (int k = 0; k < 4; ++k) {
            zre[b][k] = 0.0f; zim[b][k] = 0.0f;
            rre[b][k] = 0.0f; rim[b][k] = 0.0f;
        }

    const size_t w0 = (size_t)o * NFREQ + fA;
    const size_t wstep = (size_t)64 * NFREQ;

#pragma unroll 2
    for (int i = 0; i < 64; ++i) {
        const size_t wo = w0 + (size_t)i * wstep;
        const float4 vzr = *(const float4*)(wzr + wo);
        const float4 vzi = *(const float4*)(wzi + wo);
        const float4 vrr = *(const float4*)(wrr + wo);
        const float4 vri = *(const float4*)(wri + wo);
#pragma unroll
        for (int b = 0; b < 2; ++b) {
            const float4* hp = (const float4*)(Hf + (size_t)((b0 + b) * 64 + i) * NFREQ + fA);
            const float4 hA = hp[0], hB = hp[1];
            cmadd4(zre[b], zim[b], hA, hB, vzr, vzi);
            cmadd4(rre[b], rim[b], hA, hB, vrr, vri);
        }
    }
#pragma unroll
    for (int b = 0; b < 2; ++b) {
        float4* pz = (float4*)(Zf + (size_t)((b0 + b) * 64 + o) * NFREQ + fA);
        float4* pr = (float4*)(Rf + (size_t)((b0 + b) * 64 + o) * NFREQ + fA);
        pz[0] = make_float4(zre[b][0], zim[b][0], zre[b][1], zim[b][1]);
        pz[1] = make_float4(zre[b][2], zim[b][2], zre[b][3], zim[b][3]);
        pr[0] = make_float4(rre[b][0], rim[b][0], rre[b][1], rim[b][1]);
        pr[1] = make_float4(rre[b][2], rim[b][2], rre[b][3], rim[b][3]);
    }
}

__global__ __launch_bounds__(256) void k_pw1(const float2* __restrict__ Hf,
                                             const float* __restrict__ whr,
                                             const float* __restrict__ whi,
                                             float2* __restrict__ Of) {
    const int t = threadIdx.x;
    const int fq = t & 7;
    const int o  = blockIdx.y * 8 + ((t >> 3) & 7);
    const int b0 = blockIdx.z * 8 + (t >> 6) * 2;
    const int fA = blockIdx.x * 32 + fq * 4;

    float cre[2][4], cim[2][4];
#pragma unroll
    for (int b = 0; b < 2; ++b)
#pragma unroll
        for (int k = 0; k < 4; ++k) { cre[b][k] = 0.0f; cim[b][k] = 0.0f; }

    const size_t w0 = (size_t)o * NFREQ + fA;
    const size_t wstep = (size_t)64 * NFREQ;

#pragma unroll 2
    for (int i = 0; i < 64; ++i) {
        const size_t wo = w0 + (size_t)i * wstep;
        const float4 vr = *(const float4*)(whr + wo);
        const float4 vi = *(const float4*)(whi + wo);
#pragma unroll
        for (int b = 0; b < 2; ++b) {
            const float4* hp = (const float4*)(Hf + (size_t)((b0 + b) * 64 + i) * NFREQ + fA);
            const float4 hA = hp[0], hB = hp[1];
            cmadd4(cre[b], cim[b], hA, hB, vr, vi);
        }
    }
#pragma unroll
    for (int b = 0; b < 2; ++b) {
        float4* po = (float4*)(Of + (size_t)((b0 + b) * 64 + o) * NFREQ + fA);
        po[0] = make_float4(cre[b][0], cim[b][0], cre[b][1], cim[b][1]);
        po[1] = make_float4(cre[b][2], cim[b][2], cre[b][3], cim[b][3]);
    }
}

// ---------------- y = h @ Wo + bo, per step --------------------------------
__global__ __launch_bounds__(256) void k_yproj(const float* __restrict__ h,
                                               const float* __restrict__ Wo,
                                               const float* __restrict__ bo,
                                               float* __restrict__ out,
                                               int step) {
    __shared__ float wo[64];
    const int t = threadIdx.x;
    if (t < 64) wo[t] = Wo[t];
    __syncthreads();
    const int b = blockIdx.x >> 4, xg = blockIdx.x & 15;
    const int xx = xg * 4 + (t >> 6), y = t & 63;
    const float* hp = h + (size_t)b * 64 * IMGSZ + xx * 64 + y;
    float acc = bo[0];
#pragma unroll 8
    for (int c = 0; c < 64; ++c) acc += hp[(size_t)c * IMGSZ] * wo[c];
    out[((size_t)b * 20 + step) * IMGSZ + xx * 64 + y] = acc;
}

// ---------------------------------------------------------------------------
extern "C" void kernel_launch(void* const* d_in, const int* in_sizes, int n_in,
                              void* d_out, int out_size, void* d_ws, size_t ws_size,
                              hipStream_t stream) {
    const float* x    = (const float*)d_in[0];
    // d_in[1] = num_time_steps (always 20 per setup_inputs)
    const float* Wi   = (const float*)d_in[2];
    const float* bi   = (const float*)d_in[3];
    const float* Wo   = (const float*)d_in[4];
    const float* bo   = (const float*)d_in[5];
    const float* Wz_r = (const float*)d_in[6];
    const float* Wz_i = (const float*)d_in[7];
    const float* Wr_r = (const float*)d_in[8];
    const float* Wr_i = (const float*)d_in[9];
    const float* Wh_r = (const float*)d_in[10];
    const float* Wh_i = (const float*)d_in[11];

    float* ws = (float*)d_ws;
    float* h = ws;                              // 4,194,304 floats
    float2* B0 = (float2*)(ws + 4194304);       // 2,162,688 float2 each
    float2* B1 = B0 + 2162688;
    float2* B2 = B1 + 2162688;
    float* outp = (float*)d_out;

    k_h0fft<<<NIMG, 64, 0, stream>>>(x, Wi, bi, h, B0);   // h0, Hf -> B0

    for (int t = 0; t < 20; ++t) {
        k_pw2<<<dim3(66, 8, 2), 256, 0, stream>>>(B0, Wz_r, Wz_i, Wr_r, Wr_i,
                                                  B1, B2);  // Zf->B1 Rf->B2
        k_fifft_r<<<NIMG, 64, 0, stream>>>(B2, h, B2);      // RHf -> B2
        k_pw1<<<dim3(66, 8, 2), 256, 0, stream>>>(B2, Wh_r, Wh_i, B0); // Nf->B0
        k_fifft_n<<<NIMG, 64, 0, stream>>>(B0, B1, h, B0);  // h, Hf_next -> B0
        k_yproj<<<256, 256, 0, stream>>>(h, Wo, bo, outp, t);
    }
}